// Round 2
// baseline (499.852 us; speedup 1.0000x reference)
//
#include <hip/hip_runtime.h>
#include <math.h>

#define NUM_PAGES 1024
#define PAGE_SIZE 16
#define NUM_HEADS 32
#define HEAD_DIM 128
#define BATCH 32
#define MAX_BLOCKS 64

#define KV_STRIDE (NUM_HEADS * HEAD_DIM)  // floats between consecutive tokens

// One workgroup per (b, h). 4 waves; wave w owns pages w, w+4, w+8, ...
// Lanes split HEAD_DIM: lane holds dims [2*lane, 2*lane+1] (float2 -> 512B
// coalesced per token). Full pages run an 8-token-batched path (8 K loads in
// flight -> MLP; one online-softmax update per 8 tokens). The ragged tail
// page runs the simple 1-token path. Per-wave partials merge via LDS.
__global__ __launch_bounds__(256, 4) void paged_attn_kernel(
    const float* __restrict__ query,
    const float* __restrict__ key_cache,
    const float* __restrict__ value_cache,
    const int* __restrict__ block_tables,
    const int* __restrict__ context_lens,
    float* __restrict__ out)
{
  const int h = blockIdx.x;
  const int b = blockIdx.y;
  const int tid = threadIdx.x;
  const int lane = tid & 63;
  const int wave = tid >> 6;

  const int ctx = max(context_lens[b], 1);
  const int full_pages = ctx >> 4;          // pages with all 16 tokens valid
  const int rem = ctx & 15;                 // tokens in the ragged tail page

  const float scale = 0.088388347648318447f; // 1/sqrt(128)

  const float2 q = *(const float2*)(query + ((size_t)(b * NUM_HEADS + h)) * HEAD_DIM + lane * 2);
  const float q0 = q.x * scale, q1 = q.y * scale;

  float m = -INFINITY, l = 0.f;
  float o0 = 0.f, o1 = 0.f;

  const int* btab = block_tables + b * MAX_BLOCKS;

  // ---- full pages: 8-token batches ----
  for (int pg = wave; pg < full_pages; pg += 4) {
    const int phys = btab[pg];
    const float* base = key_cache + ((size_t)phys * PAGE_SIZE) * KV_STRIDE
                      + (size_t)h * HEAD_DIM + (size_t)lane * 2;
    const float* vbase = value_cache + ((size_t)phys * PAGE_SIZE) * KV_STRIDE
                       + (size_t)h * HEAD_DIM + (size_t)lane * 2;
    #pragma unroll
    for (int half = 0; half < 2; ++half) {
      const float* kb = base  + (size_t)(half * 8) * KV_STRIDE;
      const float* vb = vbase + (size_t)(half * 8) * KV_STRIDE;
      float2 kk[8];
      #pragma unroll
      for (int t = 0; t < 8; ++t) kk[t] = *(const float2*)(kb + (size_t)t * KV_STRIDE);
      float s[8];
      #pragma unroll
      for (int t = 0; t < 8; ++t) s[t] = q0 * kk[t].x + q1 * kk[t].y;
      #pragma unroll
      for (int d = 32; d; d >>= 1) {
        #pragma unroll
        for (int t = 0; t < 8; ++t) s[t] += __shfl_xor(s[t], d, 64);
      }
      float2 vv[8];
      #pragma unroll
      for (int t = 0; t < 8; ++t) vv[t] = *(const float2*)(vb + (size_t)t * KV_STRIDE);

      float pmax = s[0];
      #pragma unroll
      for (int t = 1; t < 8; ++t) pmax = fmaxf(pmax, s[t]);
      const float mnew = fmaxf(m, pmax);
      const float corr = __expf(m - mnew);
      float p[8];
      float psum = 0.f;
      #pragma unroll
      for (int t = 0; t < 8; ++t) { p[t] = __expf(s[t] - mnew); psum += p[t]; }
      l = l * corr + psum;
      o0 *= corr; o1 *= corr;
      #pragma unroll
      for (int t = 0; t < 8; ++t) {
        o0 = fmaf(p[t], vv[t].x, o0);
        o1 = fmaf(p[t], vv[t].y, o1);
      }
      m = mnew;
    }
  }

  // ---- ragged tail page (at index full_pages), owned by its striding wave ----
  if (rem && (full_pages & 3) == wave) {
    const int phys = btab[full_pages];
    const size_t base = ((size_t)phys * PAGE_SIZE) * KV_STRIDE
                      + (size_t)h * HEAD_DIM + (size_t)lane * 2;
    for (int t = 0; t < rem; ++t) {
      const size_t off = base + (size_t)t * KV_STRIDE;
      const float2 kk = *(const float2*)(key_cache + off);
      float s = q0 * kk.x + q1 * kk.y;
      #pragma unroll
      for (int d = 32; d; d >>= 1) s += __shfl_xor(s, d, 64);
      const float2 vv = *(const float2*)(value_cache + off);
      const float mnew = fmaxf(m, s);
      const float corr = __expf(m - mnew);
      const float p = __expf(s - mnew);
      l = l * corr + p;
      o0 = fmaf(p, vv.x, o0 * corr);
      o1 = fmaf(p, vv.y, o1 * corr);
      m = mnew;
    }
  }

  // ---- merge the 4 per-wave partial softmaxes ----
  __shared__ float sm[4], sl[4];
  __shared__ float so[4][HEAD_DIM];
  if (lane == 0) { sm[wave] = m; sl[wave] = l; }
  so[wave][lane * 2]     = o0;
  so[wave][lane * 2 + 1] = o1;
  __syncthreads();

  if (wave == 0) {
    const float M = fmaxf(fmaxf(sm[0], sm[1]), fmaxf(sm[2], sm[3]));
    const float e0 = __expf(sm[0] - M), e1 = __expf(sm[1] - M);
    const float e2 = __expf(sm[2] - M), e3 = __expf(sm[3] - M);
    const float L = sl[0] * e0 + sl[1] * e1 + sl[2] * e2 + sl[3] * e3;
    const float inv = 1.f / L;
    const int d0 = lane * 2, d1 = d0 + 1;
    const float r0 = (so[0][d0] * e0 + so[1][d0] * e1 + so[2][d0] * e2 + so[3][d0] * e3) * inv;
    const float r1 = (so[0][d1] * e0 + so[1][d1] * e1 + so[2][d1] * e2 + so[3][d1] * e3) * inv;
    float* op = out + ((size_t)(b * NUM_HEADS + h)) * HEAD_DIM;
    op[d0] = r0;
    op[d1] = r1;
  }
}

extern "C" void kernel_launch(void* const* d_in, const int* in_sizes, int n_in,
                              void* d_out, int out_size, void* d_ws, size_t ws_size,
                              hipStream_t stream) {
  const float* query       = (const float*)d_in[0];
  const float* key_cache   = (const float*)d_in[1];
  const float* value_cache = (const float*)d_in[2];
  const int*   block_tables  = (const int*)d_in[3];
  const int*   context_lens  = (const int*)d_in[4];
  float* out = (float*)d_out;

  dim3 grid(NUM_HEADS, BATCH);
  dim3 block(256);
  paged_attn_kernel<<<grid, block, 0, stream>>>(
      query, key_cache, value_cache, block_tables, context_lens, out);
}